// Round 1
// 133.238 us; speedup vs baseline: 1.0509x; 1.0509x over previous
//
#include <hip/hip_runtime.h>
#include <hip/hip_bf16.h>
#include <stdint.h>

// MLP: hidden = X @ W1^T + b1 ; out = hidden @ W2^T + b2
// X [16384,2048] f32, W1 [512,2048], b1 [512], W2 [2048,512], b2 [2048]
// R4: GEMM1 was latency-bound (Occ 20%, MfmaUtil 13%, HBM 12%): grid-limited
// to 2 blocks/CU and the 2-barrier single-buffer step serialized W-load L2
// latency every K-step. New GEMM1: 512 thr / 8 waves (2x4 of 64x32),
// double-buffered 64 KB LDS, ONE barrier per K-step with stage overlapping
// compute. Keep BK=64 XOR swizzle (0 conflicts), fused X f32->bf16 cast,
// issue-early/pack-late reg staging. GEMM2 unchanged. Casts merged.

typedef short bf16x8 __attribute__((ext_vector_type(8)));
typedef float f32x4 __attribute__((ext_vector_type(4)));

static __device__ __forceinline__ unsigned short f32_to_bf16_rne(float f) {
    unsigned int u = __float_as_uint(f);
    u += 0x7fffu + ((u >> 16) & 1u);
    return (unsigned short)(u >> 16);
}

static __device__ __forceinline__ unsigned int cvt_pk_bf16(float lo, float hi) {
    unsigned int r;
    asm("v_cvt_pk_bf16_f32 %0, %1, %2" : "=v"(r) : "v"(lo), "v"(hi));
    return r;  // low 16 = bf16(lo), high 16 = bf16(hi)
}

// one kernel casts both weight matrices (same element count each)
__global__ void cast_weights_bf16(const float* __restrict__ w1,
                                  unsigned short* __restrict__ o1,
                                  const float* __restrict__ w2,
                                  unsigned short* __restrict__ o2, int n4each) {
    int stride = gridDim.x * blockDim.x;
    for (int i = blockIdx.x * blockDim.x + threadIdx.x; i < 2 * n4each;
         i += stride) {
        const float* in = (i < n4each) ? w1 : w2;
        unsigned short* out = (i < n4each) ? o1 : o2;
        int j = (i < n4each) ? i : i - n4each;
        float4 v = ((const float4*)in)[j];
        ushort4 o;
        o.x = f32_to_bf16_rne(v.x);
        o.y = f32_to_bf16_rne(v.y);
        o.z = f32_to_bf16_rne(v.z);
        o.w = f32_to_bf16_rne(v.w);
        ((ushort4*)out)[j] = o;
    }
}

#define GLOAD_LDS16(gsrc, ldst)                                              \
    __builtin_amdgcn_global_load_lds(                                        \
        (const __attribute__((address_space(1))) void*)(gsrc),               \
        (__attribute__((address_space(3))) void*)(ldst), 16, 0, 0)

// ---------------------------------------------------------------------------
// GEMM1: H[16384][512] bf16 = X[16384][2048] f32 @ W1bf[512][2048]^T + b1
// 128x128 tile, 512 thr (2x4 waves of 64x32), BK=64, double-buffered 64 KB.
// grid = 128*4 = 512 blocks = 2 blocks/CU exactly (LDS also caps at 2).
// One __syncthreads per K-step: stage(t+1 -> buf^1) issued BEFORE compute(buf)
// so X-HBM + W-L2 latency hides under MFMA; pack/ds_write after compute.
// LDS rows are 128 B = 8 x 16B units, phys_unit = logical ^ (row&7).
// ---------------------------------------------------------------------------
__global__ __launch_bounds__(512, 4)
void gemm1_xcast(const float* __restrict__ X,
                 const unsigned short* __restrict__ W1,
                 const float* __restrict__ b1,
                 unsigned short* __restrict__ H) {
    constexpr int K = 2048, N = 512, BK = 64, NSTEP = K / BK;  // 32 steps

    __shared__ __align__(16) unsigned short ldsX[2][128 * BK];  // 2 x 16 KB
    __shared__ __align__(16) unsigned short ldsW[2][128 * BK];  // 2 x 16 KB

    const int tid  = threadIdx.x;
    const int lane = tid & 63;
    const int wid  = tid >> 6;   // 0..7
    const int wr   = wid >> 2;   // 0..1 : 64-row half
    const int wc   = wid & 3;    // 0..3 : 32-col quarter

    // chunked XCD swizzle: nwg = 512 = 8 * 64 -> XCD x gets logical [64x,64x+64)
    const int bid = blockIdx.x;
    const int swz = ((bid & 7) << 6) + (bid >> 3);
    const int bm  = swz >> 2;            // 4 col-blocks of a row-panel adjacent
    const int bn  = swz & 3;
    const int brow = bm << 7;
    const int bcol = bn << 7;

    const int lrow = lane & 15;
    const int ku   = lane >> 4;
    const int rx   = lrow & 7;

    // X staging: thread t -> row t>>2 (0..127), logical 16B-units (t&3)*2, +1
    const int xrow = tid >> 2;
    const int xu0  = (tid & 3) << 1;
    const float* xptr = X + (size_t)(brow + xrow) * K + (xu0 << 3);
    const int xb0 = xrow * 128 + ((xu0 ^ (xrow & 7)) << 4);        // byte off
    const int xb1 = xrow * 128 + (((xu0 | 1) ^ (xrow & 7)) << 4);

    // W staging: i in {0,1}: row = i*64 + (tid>>3), unit = tid&7
    const int wrow0 = tid >> 3;
    const int wu    = tid & 7;

    f32x4 acc[4][2] = {};
    f32x4 xv[4];  // in-flight X: 16 consecutive floats of row xrow

    auto loadX = [&](int k0) {
        const float* p = xptr + k0;
        xv[0] = *(const f32x4*)p;
        xv[1] = *(const f32x4*)(p + 4);
        xv[2] = *(const f32x4*)(p + 8);
        xv[3] = *(const f32x4*)(p + 12);
    };
    auto writeX = [&](unsigned short* bufX) {
        uint4 a, b;
        a.x = cvt_pk_bf16(xv[0][0], xv[0][1]);
        a.y = cvt_pk_bf16(xv[0][2], xv[0][3]);
        a.z = cvt_pk_bf16(xv[1][0], xv[1][1]);
        a.w = cvt_pk_bf16(xv[1][2], xv[1][3]);
        b.x = cvt_pk_bf16(xv[2][0], xv[2][1]);
        b.y = cvt_pk_bf16(xv[2][2], xv[2][3]);
        b.z = cvt_pk_bf16(xv[3][0], xv[3][1]);
        b.w = cvt_pk_bf16(xv[3][2], xv[3][3]);
        *(uint4*)((char*)bufX + xb0) = a;
        *(uint4*)((char*)bufX + xb1) = b;
    };
    auto stageW = [&](int k0, unsigned short* bufW) {
#pragma unroll
        for (int i = 0; i < 2; ++i) {
            const int row = i * 64 + wrow0;
            const char* src = (const char*)(W1 + (size_t)(bcol + row) * K + k0)
                              + ((wu ^ (row & 7)) << 4);
            // dest: wave-uniform base + lane*16 (contiguous) -- gload_lds legal
            GLOAD_LDS16(src, (char*)bufW + i * 8192 + tid * 16);
        }
    };
    auto compute = [&](const unsigned short* bufX, const unsigned short* bufW) {
#pragma unroll
        for (int kk = 0; kk < 2; ++kk) {
            const int un = ((ku + (kk << 2)) ^ rx) << 4;
            bf16x8 a[4], b[2];
#pragma unroll
            for (int m = 0; m < 4; ++m)
                a[m] = *(const bf16x8*)((const char*)bufX +
                       ((wr << 6) + (m << 4) + lrow) * 128 + un);
#pragma unroll
            for (int n = 0; n < 2; ++n)
                b[n] = *(const bf16x8*)((const char*)bufW +
                       ((wc << 5) + (n << 4) + lrow) * 128 + un);
#pragma unroll
            for (int m = 0; m < 4; ++m)
#pragma unroll
                for (int n = 0; n < 2; ++n)
                    acc[m][n] = __builtin_amdgcn_mfma_f32_16x16x32_bf16(
                        a[m], b[n], acc[m][n], 0, 0, 0);
        }
    };

    // prologue: tile 0 -> buf0
    loadX(0);
    stageW(0, ldsW[0]);
    writeX(ldsX[0]);
    __syncthreads();

#pragma unroll 1
    for (int t = 0; t < NSTEP; t += 2) {
        // even step: stage t+1 -> buf1 (overlaps compute of buf0)
        loadX((t + 1) * BK);
        stageW((t + 1) * BK, ldsW[1]);
        compute(ldsX[0], ldsW[0]);
        writeX(ldsX[1]);  // waits xv (vmcnt leaves gload_lds in flight)
        __syncthreads();  // drains stage(t+1); buf1 ready

        // odd step: stage t+2 -> buf0 (if any), compute buf1
        const bool more = (t + 2 < NSTEP);
        if (more) {
            loadX((t + 2) * BK);
            stageW((t + 2) * BK, ldsW[0]);
        }
        compute(ldsX[1], ldsW[1]);
        if (more) writeX(ldsX[0]);
        __syncthreads();
    }

    // epilogue: C/D layout col = lane&15, row = (lane>>4)*4 + j  [m89]
    const int r0 = (lane >> 4) << 2;
#pragma unroll
    for (int n = 0; n < 2; ++n) {
        const int col = bcol + (wc << 5) + (n << 4) + lrow;
        const float bb = b1[col];
#pragma unroll
        for (int m = 0; m < 4; ++m)
#pragma unroll
            for (int j = 0; j < 4; ++j) {
                const int row = brow + (wr << 6) + (m << 4) + r0 + j;
                H[(size_t)row * N + col] = f32_to_bf16_rne(acc[m][n][j] + bb);
            }
    }
}

// ---------------------------------------------------------------------------
// GEMM2: out[16384][2048] f32 = Hbf[16384][512] @ W2bf[2048][512]^T + b2
// 128x128 tile, 256 thr, BK=64, single-buffered 32 KB -> 5 blocks/CU.
// grid = 128*16 = 2048 blocks, chunked XCD swizzle (q=256). (unchanged)
// ---------------------------------------------------------------------------
__global__ __launch_bounds__(256)
void gemm2(const unsigned short* __restrict__ A,
           const unsigned short* __restrict__ Bt,
           const float* __restrict__ bias,
           float* __restrict__ C) {
    constexpr int N = 2048, Kd = 512, BK = 64, NSTEP = Kd / BK;  // 8 steps

    __shared__ __align__(16) unsigned short ldsA[128 * BK];  // 16 KB
    __shared__ __align__(16) unsigned short ldsB[128 * BK];  // 16 KB

    const int tid  = threadIdx.x;
    const int lane = tid & 63;
    const int wid  = tid >> 6;
    const int wr   = wid >> 1;
    const int wc   = wid & 1;

    const int bid = blockIdx.x;
    const int swz = ((bid & 7) << 8) + (bid >> 3);   // nwg=2048, q=256
    const int bn  = swz & 15;
    const int bm  = swz >> 4;
    const int brow = bm << 7;
    const int bcol = bn << 7;

    const int lrow = lane & 15;
    const int ku   = lane >> 4;
    const int rx   = lrow & 7;

    const int srow = tid >> 3;
    const int sgu  = (tid & 7) ^ (srow & 7);

    f32x4 acc[4][4] = {};

    auto stage = [&](int k0) {
#pragma unroll
        for (int i = 0; i < 4; ++i) {
            const int row = i * 32 + srow;
            const char* sa =
                (const char*)(A + (size_t)(brow + row) * Kd + k0) + (sgu << 4);
            const char* sb =
                (const char*)(Bt + (size_t)(bcol + row) * Kd + k0) + (sgu << 4);
            GLOAD_LDS16(sa, (char*)ldsA + i * 4096 + tid * 16);
            GLOAD_LDS16(sb, (char*)ldsB + i * 4096 + tid * 16);
        }
    };
    auto compute = [&]() {
#pragma unroll
        for (int kk = 0; kk < 2; ++kk) {
            const int un = ((ku + (kk << 2)) ^ rx) << 4;
            bf16x8 a[4], b[4];
#pragma unroll
            for (int m = 0; m < 4; ++m)
                a[m] = *(const bf16x8*)((const char*)ldsA +
                       ((wr << 6) + (m << 4) + lrow) * 128 + un);
#pragma unroll
            for (int n = 0; n < 4; ++n)
                b[n] = *(const bf16x8*)((const char*)ldsB +
                       ((wc << 6) + (n << 4) + lrow) * 128 + un);
#pragma unroll
            for (int m = 0; m < 4; ++m)
#pragma unroll
                for (int n = 0; n < 4; ++n)
                    acc[m][n] = __builtin_amdgcn_mfma_f32_16x16x32_bf16(
                        a[m], b[n], acc[m][n], 0, 0, 0);
        }
    };

    stage(0);
    __syncthreads();

    for (int t = 0; t < NSTEP; ++t) {
        compute();
        if (t + 1 < NSTEP) {
            __syncthreads();
            stage((t + 1) * BK);
            __syncthreads();
        }
    }

    const int r0 = (lane >> 4) << 2;
#pragma unroll
    for (int n = 0; n < 4; ++n) {
        const int col = bcol + (wc << 6) + (n << 4) + lrow;
        const float bb = bias[col];
#pragma unroll
        for (int m = 0; m < 4; ++m)
#pragma unroll
            for (int j = 0; j < 4; ++j) {
                const int row = brow + (wr << 6) + (m << 4) + r0 + j;
                C[(size_t)row * N + col] = acc[m][n][j] + bb;
            }
    }
}

extern "C" void kernel_launch(void* const* d_in, const int* in_sizes, int n_in,
                              void* d_out, int out_size, void* d_ws, size_t ws_size,
                              hipStream_t stream) {
    const float* X  = (const float*)d_in[0];   // [16384][2048]
    const float* W1 = (const float*)d_in[1];   // [512][2048]
    const float* b1 = (const float*)d_in[2];   // [512]
    const float* W2 = (const float*)d_in[3];   // [2048][512]
    const float* b2 = (const float*)d_in[4];   // [2048]

    const int B = 16384, M = 2048, Kd = 512;

    // workspace: W1bf (2MB), W2bf (2MB), Hbf (16.8MB)
    char* ws = (char*)d_ws;
    unsigned short* W1bf = (unsigned short*)ws;
    unsigned short* W2bf = W1bf + (size_t)Kd * M;
    unsigned short* Hbf  = W2bf + (size_t)M * Kd;

    // both weight casts in one launch: 2 * 256K float4s, one per thread
    cast_weights_bf16<<<2048, 256, 0, stream>>>(W1, W1bf, W2, W2bf,
                                                Kd * M / 4);

    gemm1_xcast<<<(B / 128) * (Kd / 128), 512, 0, stream>>>(X, W1bf, b1, Hbf);
    gemm2<<<(B / 128) * (M / 128), 256, 0, stream>>>(Hbf, W2bf, b2,
                                                     (float*)d_out);
}